// Round 6
// baseline (94.335 us; speedup 1.0000x reference)
//
#include <hip/hip_runtime.h>

#define VOCAB 4096
#define SLICES 16
#define SLICE 256            // codes per slice (16-way split per point-set)
#define TRK 32               // codes per TRACKED super-group (margin unit)
#define NCHUNK 32            // 8-code chunks per slice
#define P 2                  // points per lane
#define PTS (64 * P)         // 128 points per block
#define THREADS 1024
#define NCHT 513             // total chunks incl. 1 pad (for branch-free prefetch)

typedef float f2 __attribute__((ext_vector_type(2)));

// Packed fp32 helpers -> v_pk_fma_f32 / v_pk_max_f32 (bit-identical per elem).
__device__ __forceinline__ f2 fma2(f2 a, f2 b, f2 c) {
  return __builtin_elementwise_fma(a, b, c);
}
__device__ __forceinline__ f2 max2(f2 a, f2 b) {
  return __builtin_elementwise_max(a, b);
}

// Empty-asm register barrier: forces the value into a VGPR, preventing
// fma-contraction / reassociation across it. Emits no instruction.
__device__ __forceinline__ float opaque(float x) {
  asm volatile("" : "+v"(x));
  return x;
}

// v_med3_f32: with invariant t2 <= t1, med3(t1, t2, gm) == max(t2, min(t1,gm))
// (exact selection). 1 slot instead of 2.
__device__ __forceinline__ float med3f(float a, float b, float c) {
  float d;
  asm("v_med3_f32 %0, %1, %2, %3" : "=v"(d) : "v"(a), "v"(b), "v"(c));
  return d;
}

// 8-code chunk of e-coords only, pair-SoA: {e0 x4pairs, e1 x4, e2 x4} = 96 B.
// Wave-uniform -> s_load into SGPRs; each f2 is one legal VOP3P SGPR operand.
// h lives in a SEPARATE table fetched via vector loads (VGPR), so the
// innermost fma2(Z, e2_sgpr, h_vgpr) has exactly 1 SGPR operand -> no splat
// movs (2-SGPR operands are an illegal encoding the compiler fixes with movs).
struct EChunk { f2 e0[4], e1[4], e2[4]; };

// Prep: per-code {e0,e1,e2,h}, h = -0.5f*c, c rounded exactly like numpy
// (validated R10/R12/R13). Writes cw (rescan/phase-2 table), cwe (e-chunks),
// cwh (h-pairs, 32 B/chunk).
__global__ __launch_bounds__(256) void vq_prep_kernel(
    const float* __restrict__ cb, float4* __restrict__ cw,
    float* __restrict__ cwe, float* __restrict__ cwh,
    float* __restrict__ loss_slot) {
  int j = blockIdx.x * 256 + threadIdx.x;
  if (j == 0) *loss_slot = 0.0f;
  if (j < VOCAB) {
    float e0 = cb[3 * j + 0];
    float e1 = cb[3 * j + 1];
    float e2 = cb[3 * j + 2];
    float p0 = opaque(e0 * e0);
    float p1 = opaque(e1 * e1);
    float p2 = opaque(e2 * e2);
    float c = opaque(opaque(p0 + p1) + p2);
    float h = -0.5f * c;
    cw[j] = make_float4(e0, e1, e2, h);
    int i = j >> 1, o = j & 1;          // pair id, slot within pair
    int ch = i >> 2, q = i & 3;         // chunk id, pair pos in chunk
    cwe[ch * 24 + 0 * 8 + q * 2 + o] = e0;
    cwe[ch * 24 + 1 * 8 + q * 2 + o] = e1;
    cwe[ch * 24 + 2 * 8 + q * 2 + o] = e2;
    cwh[ch * 8 + q * 2 + o] = h;
  }
}

// Bit-exact numpy f32 distance (validated absmax=0.0 R10/R12/R13).
__device__ __forceinline__ float dist_f32(float x0, float x1, float x2,
                                          float a, float4 cd) {
  float m = fmaf(x2, cd.z, fmaf(x1, cd.y, x0 * cd.x));
  return fmaf(-2.0f, m, a) + (-2.0f * cd.w);
}

// Main: 512 blocks x 1024 threads; block = 128 points (2/lane) x 16 slices.
// R0-R5: VALU-issue + operand-delivery bound; occupancy/path swaps null.
// This round: (1) h via uniform-addr VECTOR loads (idle vmem pipe, kills
// SGPR-splat movs), (2) e-only 96B chunks + branch-free distance-1 s_load
// prefetch (pad chunk), unroll 4, (3) first-chunk mm assign (no reset movs).
__global__ __launch_bounds__(THREADS, 8) void vq_kernel(
    const float* __restrict__ feats, const float4* __restrict__ cw,
    const EChunk* __restrict__ ech, const float4* __restrict__ hch,
    float* __restrict__ out_quant, float* __restrict__ out_idx,
    float* __restrict__ out_loss, int npts) {
  __shared__ float sT1[SLICES * PTS];       // 8 KB per-slice best t
  __shared__ float sT2[SLICES * PTS];       // 8 KB per-slice 2nd-best
  __shared__ int sG[SLICES * PTS];          // 8 KB per-slice group base
  __shared__ unsigned long long sSlot[PTS]; // 1 KB fallback (d,idx) keys
  __shared__ float4 sFP[PTS];               // 2 KB flagged-point coords
  __shared__ int sList[PTS];                // 0.5 KB flagged point ids
  __shared__ int sCount;
  __shared__ double sPart[2];               // per-wave loss partials

  const int tid = threadIdx.x;
  const int lane = tid & 63;
  // Wave-uniform slice id (readfirstlane: proven uniform -> scalar path).
  const int s = __builtin_amdgcn_readfirstlane(tid >> 6);

  if (tid == 0) sCount = 0;

  const int pbase = blockIdx.x * PTS;
  // Lane's P points: pbase + k*64 + lane, k = 0..P-1 (same for all waves).
  float px[P], py[P], pz[P], nn[P];
#pragma unroll
  for (int k = 0; k < P; ++k) {
    const int p = pbase + k * 64 + lane;
    px[k] = feats[3 * p + 0];
    py[k] = feats[3 * p + 1];
    pz[k] = feats[3 * p + 2];
    // ||x||^2 exactly as numpy: products rounded, then ((p0+p1)+p2)
    float q0 = opaque(px[k] * px[k]);
    float q1 = opaque(py[k] * py[k]);
    float q2 = opaque(pz[k] * pz[k]);
    nn[k] = opaque(opaque(q0 + q1) + q2);
  }

  // Phase 1: surrogate max-scan over this wave's 256-code slice.
  // e: SGPR (s_load, 1 SGPR operand per fma). h: VGPR via uniform-address
  // vector loads (opaque VGPR base defeats scalarization -> global_load,
  // HW-broadcast, L1-hot, imm-offset addressing).
  f2 X[P], Y[P], Z[P];
#pragma unroll
  for (int k = 0; k < P; ++k) {
    X[k] = (f2){px[k], px[k]};
    Y[k] = (f2){py[k], py[k]};
    Z[k] = (f2){pz[k], pz[k]};
  }
  const EChunk* we = ech + s * NCHUNK;
  unsigned long long wha = (unsigned long long)(hch + s * (NCHUNK * 2));
  asm volatile("" : "+v"(wha));             // force VGPR base -> vector loads
  const float4* wh = (const float4*)wha;

  float t1[P], t2[P];
  int gg[P];
  f2 mm[P];
#pragma unroll
  for (int k = 0; k < P; ++k) {
    t1[k] = -3.4e38f; t2[k] = -3.4e38f; gg[k] = 0;
    mm[k] = (f2){-3.4e38f, -3.4e38f};
  }

  EChunk ec = we[0];
  float4 ha = wh[0], hb = wh[1];
#pragma unroll 4
  for (int c = 0; c < NCHUNK; ++c) {
    // Branch-free distance-1 prefetch (chunk NCHUNK-1 reads the pad chunk
    // or the next slice's chunk 0 — loaded, never consumed).
    EChunk en = we[c + 1];
    float4 na = wh[2 * c + 2], nb = wh[2 * c + 3];
    f2 H0 = (f2){ha.x, ha.y}, H1 = (f2){ha.z, ha.w};
    f2 H2 = (f2){hb.x, hb.y}, H3 = (f2){hb.z, hb.w};
#pragma unroll
    for (int k = 0; k < P; ++k) {
      // u = fma(x0,e0, fma(x1,e1, fma(x2,e2, h))) per code, 2 codes/f2
      f2 u0 = fma2(X[k], ec.e0[0], fma2(Y[k], ec.e1[0], fma2(Z[k], ec.e2[0], H0)));
      f2 u1 = fma2(X[k], ec.e0[1], fma2(Y[k], ec.e1[1], fma2(Z[k], ec.e2[1], H1)));
      f2 u2 = fma2(X[k], ec.e0[2], fma2(Y[k], ec.e1[2], fma2(Z[k], ec.e2[2], H2)));
      f2 u3 = fma2(X[k], ec.e0[3], fma2(Y[k], ec.e1[3], fma2(Z[k], ec.e2[3], H3)));
      f2 tm = max2(max2(u0, u1), max2(u2, u3));
      // First chunk of each super-group assigns (no reset movs, exact).
      mm[k] = ((c & 3) == 0) ? tm : max2(mm[k], tm);
    }
    if ((c & 3) == 3) {
      const int g = c >> 2;                  // super-group id 0..7
#pragma unroll
      for (int k = 0; k < P; ++k) {
        float gm = fmaxf(mm[k].x, mm[k].y);  // super-group max (exact)
        t2[k] = med3f(t1[k], t2[k], gm);     // streaming top-2 (med3 trick)
        if (gm > t1[k]) gg[k] = g;           // strict >: earliest group
        t1[k] = fmaxf(t1[k], gm);
      }
    }
    ec = en; ha = na; hb = nb;
  }
#pragma unroll
  for (int k = 0; k < P; ++k) {
    sT1[s * PTS + k * 64 + lane] = t1[k];
    sT2[s * PTS + k * 64 + lane] = t2[k];
    sG[s * PTS + k * 64 + lane] = s * SLICE + gg[k] * TRK;
  }
  __syncthreads();

  // Epilogue combine: tid < 128 owns block-point pt == tid; its coords are
  // its own registers' point k == s (waves 0..1 cover tid 0..127).
  int bi = 0;
  float q0 = 0.0f, q1 = 0.0f, q2 = 0.0f;
  bool flagged = false;
  float x0 = px[0], x1 = py[0], x2 = pz[0], a = nn[0];
#pragma unroll
  for (int k = 1; k < P; ++k) {
    if (s == k) { x0 = px[k]; x1 = py[k]; x2 = pz[k]; a = nn[k]; }
  }
  if (tid < PTS) {
    float b1 = sT1[tid], b2 = sT2[tid];
    int gbase = sG[tid];
#pragma unroll
    for (int k = 1; k < SLICES; ++k) {  // ascending slice order
      float u1 = sT1[k * PTS + tid];
      float u2 = sT2[k * PTS + tid];
      b2 = fmaxf(fmaxf(b2, u2), fminf(b1, u1));
      if (u1 > b1) gbase = sG[k * PTS + tid];
      b1 = fmaxf(b1, u1);
    }
    // Margin test (validated R10/R12/R13): eps = a*2^-21 + 2^-20 (2x safe);
    // group size does not enter the bound (per-code skew).
    float eps = fmaf(a, 0x1p-21f, 0x1p-20f);
    flagged = !((b1 - b2) > eps);
    if (flagged) {
      int pos = atomicAdd(&sCount, 1);
      sList[pos] = tid;
      sSlot[tid] = ~0ULL;
      sFP[tid] = make_float4(x0, x1, x2, a);  // phase-2 reads LDS, not HBM
    } else {
      // Bit-exact rescan of the certified 32-code group (global, L1/L2-hot);
      // ascending, strict <: np.argmin first-occurrence.
      float bd = 3.4e38f;
#pragma unroll 8
      for (int k = 0; k < TRK; ++k) {
        float4 cd = cw[gbase + k];
        float d = dist_f32(x0, x1, x2, a, cd);
        if (d < bd) { bd = d; bi = gbase + k; q0 = cd.x; q1 = cd.y; q2 = cd.z; }
      }
    }
  }
  __syncthreads();

  // Phase 2: cooperative bit-exact full rescan for flagged points.
  // 1024 threads x 4 codes each; sortable (d,idx) key min-reduce.
  const int cnt = sCount;
  for (int f = 0; f < cnt; ++f) {
    const int fpt = sList[f];
    float4 fp = sFP[fpt];           // same addr all threads -> LDS broadcast
    float y0 = fp.x, y1 = fp.y, y2 = fp.z;
    float ay = fp.w;                // same opaque-rounded value as at load
    float bd = 3.4e38f;
    int bj = 0;
#pragma unroll
    for (int k = 0; k < VOCAB / THREADS; ++k) {
      int j = tid + k * THREADS;
      float4 cd = cw[j];
      float d = dist_f32(y0, y1, y2, ay, cd);
      if (d < bd) { bd = d; bj = j; }
    }
    unsigned b = __float_as_uint(bd);
    b = (b & 0x80000000u) ? ~b : (b | 0x80000000u);  // total-order transform
    unsigned long long key = ((unsigned long long)b << 32) | (unsigned)bj;
#pragma unroll
    for (int off = 1; off < 64; off <<= 1) {         // wave min-butterfly
      unsigned long long o = __shfl_xor(key, off);
      key = (o < key) ? o : key;
    }
    if (lane == 0) atomicMin(&sSlot[fpt], key);      // 16 atomics/point
  }
  __syncthreads();

  double lsum = 0.0;
  if (tid < PTS) {
    if (flagged) {
      bi = (int)(unsigned)(sSlot[tid] & 0xFFFFFFFFu);
      float4 cd = cw[bi];
      q0 = cd.x; q1 = cd.y; q2 = cd.z;
    }
    const int p = pbase + tid;
    // straight-through: t = q - x (f32), out = x + t (f32), like reference
    float t0 = q0 - x0, t1d = q1 - x1, t2d = q2 - x2;
    out_quant[3 * p + 0] = x0 + t0;
    out_quant[3 * p + 1] = x1 + t1d;
    out_quant[3 * p + 2] = x2 + t2d;
    out_idx[p] = (float)bi;
    lsum = (double)t0 * t0 + (double)t1d * t1d + (double)t2d * t2d;
  }
  // Loss: wave shuffle-tree reduce (double), waves 0..1 hold the data.
#pragma unroll
  for (int off = 32; off >= 1; off >>= 1) lsum += __shfl_down(lsum, off);
  if (lane == 0 && s < P) sPart[s] = lsum;
  __syncthreads();

  if (tid == 0) {
    double acc = sPart[0] + sPart[1];
    // loss = mean((q-x)^2) + 0.25*mean((x-q)^2) = 1.25 * sum / (npts*3)
    atomicAdd(out_loss, (float)(acc * (1.25 / ((double)npts * 3.0))));
  }
}

extern "C" void kernel_launch(void* const* d_in, const int* in_sizes, int n_in,
                              void* d_out, int out_size, void* d_ws,
                              size_t ws_size, hipStream_t stream) {
  const float* feats = (const float*)d_in[0];      // (B*L, 3) f32
  const float* cb = (const float*)d_in[1];         // (4096, 3) f32
  const int npts = in_sizes[0] / 3;                // 65536

  float* out = (float*)d_out;
  float* out_quant = out;                          // npts*3 elems
  float* out_idx = out + in_sizes[0];              // npts elems
  float* out_loss = out + in_sizes[0] + npts;      // 1 elem

  float4* cw = (float4*)d_ws;                      // 4096 * 16 B = 64 KB
  float* cwe = (float*)(cw + VOCAB);               // 513 * 96 B e-chunks
  float* cwh = cwe + NCHT * 24;                    // 513 * 32 B h-pairs

  vq_prep_kernel<<<VOCAB / 256, 256, 0, stream>>>(cb, cw, cwe, cwh, out_loss);
  vq_kernel<<<npts / PTS, THREADS, 0, stream>>>(
      feats, cw, (const EChunk*)cwe, (const float4*)cwh, out_quant, out_idx,
      out_loss, npts);
}

// Round 8
// 88.035 us; speedup vs baseline: 1.0716x; 1.0716x over previous
//
#include <hip/hip_runtime.h>

#define VOCAB 4096
#define SLICES 16
#define SLICE 256            // codes per slice (16-way split per point-set)
#define TRK 32               // codes per TRACKED super-group (margin unit)
#define NSUP (SLICE / TRK)   // 8 super-groups per slice
#define P 2                  // points per lane
#define PTS (64 * P)         // 128 points per block
#define THREADS 1024

typedef float f2 __attribute__((ext_vector_type(2)));

// Forced packed fp32 FMA: v_pk_fma_f32 (VOP3P; gfx90a+, full-rate on gfx950
// per R3/R6 busy-time audit). Per-element bit-identical to v_fma_f32.
// NOTE (R7): v_pk_max_f32 does NOT exist on gfx950 — packed fp32 is only
// fma/mul/add/mov. Max tree therefore uses scalar v_max3_f32 folding.
// e-operand uses "s": the code tables are wave-uniform s_loads in SGPR
// pairs; VOP3P allows exactly one 64-bit scalar operand.
__device__ __forceinline__ f2 pkfma_sv(f2 x, f2 e, f2 c) {
  f2 d;
  asm("v_pk_fma_f32 %0, %1, %2, %3" : "=v"(d) : "v"(x), "s"(e), "v"(c));
  return d;
}

// Empty-asm register barrier: forces the value into a VGPR, preventing
// fma-contraction / reassociation across it. Emits no instruction.
__device__ __forceinline__ float opaque(float x) {
  asm volatile("" : "+v"(x));
  return x;
}

// v_max3_f32: exact 3-input max (identical result to nested fmaxf).
__device__ __forceinline__ float max3f(float a, float b, float c) {
  float d;
  asm("v_max3_f32 %0, %1, %2, %3" : "=v"(d) : "v"(a), "v"(b), "v"(c));
  return d;
}

// v_med3_f32: with invariant t2 <= t1, med3(t1, t2, gm) == max(t2, min(t1,gm))
// (exact selection). 1 slot instead of 2.
__device__ __forceinline__ float med3f(float a, float b, float c) {
  float d;
  asm("v_med3_f32 %0, %1, %2, %3" : "=v"(d) : "v"(a), "v"(b), "v"(c));
  return d;
}

// Code pair, SoA-interleaved: {e0a,e0b}, {e1a,e1b}, {e2a,e2b}, {ha,hb}.
// Wave-uniform loads keep each f2 in an SGPR pair = one VOP3P operand.
struct CPair { f2 e0, e1, e2, h; };   // 32 B

// Prep: pack per-code {e0, e1, e2, h} where h = -0.5f*c and
// c = ((e0*e0+e1*e1)+e2*e2) rounded exactly like numpy (each product/sum
// individually rounded f32). h is an exact scale of c (exponent shift),
// so c = -2*h is recoverable bit-exactly. (Validated R10/R12/R13.)
// Also writes the pair-interleaved copy used by phase 1.
__global__ __launch_bounds__(256) void vq_prep_kernel(
    const float* __restrict__ cb, float4* __restrict__ cw,
    float* __restrict__ cwp, float* __restrict__ loss_slot) {
  int j = blockIdx.x * 256 + threadIdx.x;
  if (j == 0) *loss_slot = 0.0f;
  if (j < VOCAB) {
    float e0 = cb[3 * j + 0];
    float e1 = cb[3 * j + 1];
    float e2 = cb[3 * j + 2];
    float p0 = opaque(e0 * e0);
    float p1 = opaque(e1 * e1);
    float p2 = opaque(e2 * e2);
    float c = opaque(opaque(p0 + p1) + p2);
    float h = -0.5f * c;
    cw[j] = make_float4(e0, e1, e2, h);
    int i = j >> 1, o = j & 1;          // pair id, slot within pair
    cwp[i * 8 + 0 + o] = e0;
    cwp[i * 8 + 2 + o] = e1;
    cwp[i * 8 + 4 + o] = e2;
    cwp[i * 8 + 6 + o] = h;
  }
}

// Bit-exact numpy f32 distance (validated absmax=0.0 R10/R12/R13):
//   m = x.e (fma ascending k, first term single-rounded mul)
//   d = (a - 2m) + c;  c = -2*h exact (fma-contract-safe).
__device__ __forceinline__ float dist_f32(float x0, float x1, float x2,
                                          float a, float4 cd) {
  float m = fmaf(x2, cd.z, fmaf(x1, cd.y, x0 * cd.x));
  return fmaf(-2.0f, m, a) + (-2.0f * cd.w);
}

// Main: 512 blocks x 1024 threads; block = 128 points (2/lane) x 16 slices.
// Structure = R5 (best verified, 87.8us). Changes: (1) FMAs emitted as
// forced v_pk_fma_f32 (v,s,v — legal; h copied to VGPR once per chunk),
// (2) max tree folded with scalar v_max3_f32 into a running scalar per
// point (no packed max exists on gfx950; max is exact+associative so the
// fold order change cannot alter gm/flags/indices).
__global__ __launch_bounds__(THREADS, 8) void vq_kernel(
    const float* __restrict__ feats, const float4* __restrict__ cw,
    const CPair* __restrict__ cp, float* __restrict__ out_quant,
    float* __restrict__ out_idx, float* __restrict__ out_loss, int npts) {
  __shared__ float sT1[SLICES * PTS];       // 8 KB per-slice best t
  __shared__ float sT2[SLICES * PTS];       // 8 KB per-slice 2nd-best
  __shared__ int sG[SLICES * PTS];          // 8 KB per-slice group base
  __shared__ unsigned long long sSlot[PTS]; // 1 KB fallback (d,idx) keys
  __shared__ float4 sFP[PTS];               // 2 KB flagged-point coords
  __shared__ int sList[PTS];                // 0.5 KB flagged point ids
  __shared__ int sCount;
  __shared__ double sPart[2];               // per-wave loss partials

  const int tid = threadIdx.x;
  const int lane = tid & 63;
  // Wave-uniform slice id (readfirstlane: proven uniform -> scalar path).
  const int s = __builtin_amdgcn_readfirstlane(tid >> 6);

  if (tid == 0) sCount = 0;

  const int pbase = blockIdx.x * PTS;
  // Lane's P points: pbase + k*64 + lane, k = 0..P-1 (same for all waves).
  float px[P], py[P], pz[P], nn[P];
#pragma unroll
  for (int k = 0; k < P; ++k) {
    const int p = pbase + k * 64 + lane;
    px[k] = feats[3 * p + 0];
    py[k] = feats[3 * p + 1];
    pz[k] = feats[3 * p + 2];
    // ||x||^2 exactly as numpy: products rounded, then ((p0+p1)+p2)
    float q0 = opaque(px[k] * px[k]);
    float q1 = opaque(py[k] * py[k]);
    float q2 = opaque(pz[k] * pz[k]);
    nn[k] = opaque(opaque(q0 + q1) + q2);
  }

  // Phase 1: surrogate max-scan over this wave's 256-code slice, FMAs
  // packed over code pairs; top-2/gg tracked at 32-code super-groups.
  f2 X[P], Y[P], Z[P];
#pragma unroll
  for (int k = 0; k < P; ++k) {
    X[k] = (f2){px[k], px[k]};
    Y[k] = (f2){py[k], py[k]};
    Z[k] = (f2){pz[k], pz[k]};
  }
  const CPair* cs = cp + s * (SLICE / 2);   // 128 pairs per slice
  float t1[P], t2[P];
  int gg[P];
#pragma unroll
  for (int k = 0; k < P; ++k) { t1[k] = -3.4e38f; t2[k] = -3.4e38f; gg[k] = 0; }
#pragma unroll 2
  for (int g = 0; g < NSUP; ++g) {
    const CPair* gp = cs + g * (TRK / 2);   // 16 pairs = 32 codes, uniform
    float mm[P];
#pragma unroll
    for (int k = 0; k < P; ++k) mm[k] = -3.4e38f;
#pragma unroll
    for (int c = 0; c < TRK / 8; ++c) {     // 4 chunks of 4 pairs (8 codes)
      const CPair* ck = gp + c * 4;
      CPair a0 = ck[0], a1 = ck[1], a2 = ck[2], a3 = ck[3];
      // h addend needs a VGPR (src2; src1 already takes the one allowed
      // scalar operand): one copy per chunk, shared by both points.
      f2 H0 = a0.h, H1 = a1.h, H2 = a2.h, H3 = a3.h;
      asm volatile("" : "+v"(H0), "+v"(H1), "+v"(H2), "+v"(H3));
#pragma unroll
      for (int k = 0; k < P; ++k) {
        // u = fma(x0,e0, fma(x1,e1, fma(x2,e2, h))) per code, 2 codes/slot
        f2 u0 = pkfma_sv(X[k], a0.e0, pkfma_sv(Y[k], a0.e1, pkfma_sv(Z[k], a0.e2, H0)));
        f2 u1 = pkfma_sv(X[k], a1.e0, pkfma_sv(Y[k], a1.e1, pkfma_sv(Z[k], a1.e2, H1)));
        f2 u2 = pkfma_sv(X[k], a2.e0, pkfma_sv(Y[k], a2.e1, pkfma_sv(Z[k], a2.e2, H2)));
        f2 u3 = pkfma_sv(X[k], a3.e0, pkfma_sv(Y[k], a3.e1, pkfma_sv(Z[k], a3.e2, H3)));
        // Fold 8 components + running max with 4 max3 (exact).
        float m1 = max3f(u0.x, u0.y, u1.x);
        float m2 = max3f(u1.y, u2.x, u2.y);
        float m3 = max3f(u3.x, u3.y, mm[k]);
        mm[k] = max3f(m1, m2, m3);
      }
    }
#pragma unroll
    for (int k = 0; k < P; ++k) {
      float gm = mm[k];                      // super-group max (exact)
      t2[k] = med3f(t1[k], t2[k], gm);       // streaming top-2 (med3 trick)
      if (gm > t1[k]) gg[k] = g;             // strict >: earliest group
      t1[k] = fmaxf(t1[k], gm);
    }
  }
#pragma unroll
  for (int k = 0; k < P; ++k) {
    sT1[s * PTS + k * 64 + lane] = t1[k];
    sT2[s * PTS + k * 64 + lane] = t2[k];
    sG[s * PTS + k * 64 + lane] = s * SLICE + gg[k] * TRK;
  }
  __syncthreads();

  // Epilogue combine: tid < 128 owns block-point pt == tid; its coords are
  // its own registers' point k == s (waves 0..1 cover tid 0..127).
  int bi = 0;
  float q0 = 0.0f, q1 = 0.0f, q2 = 0.0f;
  bool flagged = false;
  float x0 = px[0], x1 = py[0], x2 = pz[0], a = nn[0];
#pragma unroll
  for (int k = 1; k < P; ++k) {
    if (s == k) { x0 = px[k]; x1 = py[k]; x2 = pz[k]; a = nn[k]; }
  }
  if (tid < PTS) {
    float b1 = sT1[tid], b2 = sT2[tid];
    int gbase = sG[tid];
#pragma unroll
    for (int k = 1; k < SLICES; ++k) {  // ascending slice order
      float u1 = sT1[k * PTS + tid];
      float u2 = sT2[k * PTS + tid];
      b2 = fmaxf(fmaxf(b2, u2), fminf(b1, u1));
      if (u1 > b1) gbase = sG[k * PTS + tid];
      b1 = fmaxf(b1, u1);
    }
    // Margin test (validated R10/R12/R13): eps = a*2^-21 + 2^-20 (2x safe);
    // group size does not enter the bound (per-code skew).
    float eps = fmaf(a, 0x1p-21f, 0x1p-20f);
    flagged = !((b1 - b2) > eps);
    if (flagged) {
      int pos = atomicAdd(&sCount, 1);
      sList[pos] = tid;
      sSlot[tid] = ~0ULL;
      sFP[tid] = make_float4(x0, x1, x2, a);  // phase-2 reads LDS, not HBM
    } else {
      // Bit-exact rescan of the certified 32-code group (global, L1/L2-hot);
      // ascending, strict <: np.argmin first-occurrence.
      float bd = 3.4e38f;
#pragma unroll 8
      for (int k = 0; k < TRK; ++k) {
        float4 cd = cw[gbase + k];
        float d = dist_f32(x0, x1, x2, a, cd);
        if (d < bd) { bd = d; bi = gbase + k; q0 = cd.x; q1 = cd.y; q2 = cd.z; }
      }
    }
  }
  __syncthreads();

  // Phase 2: cooperative bit-exact full rescan for flagged points.
  // 1024 threads x 4 codes each; sortable (d,idx) key min-reduce: min key
  // == min d, tie -> min idx (first occurrence).
  const int cnt = sCount;
  for (int f = 0; f < cnt; ++f) {
    const int fpt = sList[f];
    float4 fp = sFP[fpt];           // same addr all threads -> LDS broadcast
    float y0 = fp.x, y1 = fp.y, y2 = fp.z;
    float ay = fp.w;                // same opaque-rounded value as at load
    float bd = 3.4e38f;
    int bj = 0;
#pragma unroll
    for (int k = 0; k < VOCAB / THREADS; ++k) {
      int j = tid + k * THREADS;
      float4 cd = cw[j];
      float d = dist_f32(y0, y1, y2, ay, cd);
      if (d < bd) { bd = d; bj = j; }
    }
    unsigned b = __float_as_uint(bd);
    b = (b & 0x80000000u) ? ~b : (b | 0x80000000u);  // total-order transform
    unsigned long long key = ((unsigned long long)b << 32) | (unsigned)bj;
#pragma unroll
    for (int off = 1; off < 64; off <<= 1) {         // wave min-butterfly
      unsigned long long o = __shfl_xor(key, off);
      key = (o < key) ? o : key;
    }
    if (lane == 0) atomicMin(&sSlot[fpt], key);      // 16 atomics/point
  }
  __syncthreads();

  double lsum = 0.0;
  if (tid < PTS) {
    if (flagged) {
      bi = (int)(unsigned)(sSlot[tid] & 0xFFFFFFFFu);
      float4 cd = cw[bi];
      q0 = cd.x; q1 = cd.y; q2 = cd.z;
    }
    const int p = pbase + tid;
    // straight-through: t = q - x (f32), out = x + t (f32), like reference
    float t0 = q0 - x0, t1d = q1 - x1, t2d = q2 - x2;
    out_quant[3 * p + 0] = x0 + t0;
    out_quant[3 * p + 1] = x1 + t1d;
    out_quant[3 * p + 2] = x2 + t2d;
    out_idx[p] = (float)bi;
    lsum = (double)t0 * t0 + (double)t1d * t1d + (double)t2d * t2d;
  }
  // Loss: wave shuffle-tree reduce (double), waves 0..1 hold the data.
#pragma unroll
  for (int off = 32; off >= 1; off >>= 1) lsum += __shfl_down(lsum, off);
  if (lane == 0 && s < P) sPart[s] = lsum;
  __syncthreads();

  if (tid == 0) {
    double acc = sPart[0] + sPart[1];
    // loss = mean((q-x)^2) + 0.25*mean((x-q)^2) = 1.25 * sum / (npts*3)
    atomicAdd(out_loss, (float)(acc * (1.25 / ((double)npts * 3.0))));
  }
}

extern "C" void kernel_launch(void* const* d_in, const int* in_sizes, int n_in,
                              void* d_out, int out_size, void* d_ws,
                              size_t ws_size, hipStream_t stream) {
  const float* feats = (const float*)d_in[0];      // (B*L, 3) f32
  const float* cb = (const float*)d_in[1];         // (4096, 3) f32
  const int npts = in_sizes[0] / 3;                // 65536

  float* out = (float*)d_out;
  float* out_quant = out;                          // npts*3 elems
  float* out_idx = out + in_sizes[0];              // npts elems
  float* out_loss = out + in_sizes[0] + npts;      // 1 elem

  float4* cw = (float4*)d_ws;                      // 4096 * 16 B = 64 KB
  float* cwp = (float*)(cw + VOCAB);               // paired SoA copy, 64 KB

  vq_prep_kernel<<<VOCAB / 256, 256, 0, stream>>>(cb, cw, cwp, out_loss);
  vq_kernel<<<npts / PTS, THREADS, 0, stream>>>(feats, cw, (const CPair*)cwp,
                                                out_quant, out_idx, out_loss,
                                                npts);
}